// Round 6
// baseline (338.301 us; speedup 1.0000x reference)
//
#include <hip/hip_runtime.h>
#include <math.h>

#define PI_F 3.14159265358979323846f
#define TWO_PI_F 6.28318530717958647692f
#define RSQ2 0.70710678118654752440f

// Compiler-only fence: stops IR/scheduler reordering of LDS ops across it.
// HW ordering is free: a wave's DS ops execute in order, and the backend
// inserts minimal s_waitcnt lgkmcnt(N) before VALU use of loaded values.
#define CFENCE() __asm__ volatile("" ::: "memory")
// additive swizzle for FFT stage arrays: injective on [0,512), max 574.
#define LADDR(a) ((a) + ((a) >> 3))
// XOR swizzle for the output transpose (float4 units): bijective, spreads
// lane-stride-16 writes across all 8 float4-bank-groups -> 2 lanes/bank (free).
#define TSWZ(L) ((L) ^ (((L) >> 4) & 7))

__device__ __forceinline__ float2 cadd(float2 a, float2 b){ return make_float2(a.x+b.x, a.y+b.y); }
__device__ __forceinline__ float2 csub(float2 a, float2 b){ return make_float2(a.x-b.x, a.y-b.y); }
__device__ __forceinline__ float2 cmul(float2 a, float2 b){ return make_float2(a.x*b.x - a.y*b.y, a.x*b.y + a.y*b.x); }
__device__ __forceinline__ float2 cw1(float2 a){ return make_float2(RSQ2*(a.x+a.y), RSQ2*(a.y-a.x)); }  // *W8^1
__device__ __forceinline__ float2 cw2(float2 a){ return make_float2(a.y, -a.x); }                        // *(-i)
__device__ __forceinline__ float2 cw3(float2 a){ return make_float2(RSQ2*(a.y-a.x), -RSQ2*(a.x+a.y)); }  // *W8^3

// in-place DIF-8. On return, slot m holds U_{br[m]}, br = {0,4,2,6,1,5,3,7}.
__device__ __forceinline__ void dft8(float2* v){
    float2 a0=cadd(v[0],v[4]), a1=cadd(v[1],v[5]), a2=cadd(v[2],v[6]), a3=cadd(v[3],v[7]);
    float2 b0=csub(v[0],v[4]);
    float2 b1=cw1(csub(v[1],v[5]));
    float2 b2=cw2(csub(v[2],v[6]));
    float2 b3=cw3(csub(v[3],v[7]));
    float2 c0=cadd(a0,a2), c2=csub(a0,a2), c1=cadd(a1,a3), c3=cw2(csub(a1,a3));
    float2 d0=cadd(b0,b2), d2=csub(b0,b2), d1=cadd(b1,b3), d3=cw2(csub(b1,b3));
    v[0]=cadd(c0,c1); v[1]=csub(c0,c1);   // U0, U4
    v[2]=cadd(c2,c3); v[3]=csub(c2,c3);   // U2, U6
    v[4]=cadd(d0,d1); v[5]=csub(d0,d1);   // U1, U5
    v[6]=cadd(d2,d3); v[7]=csub(d2,d3);   // U3, U7
}

// Stockham radix-8 stage store: address-slot c gets U_c * w1^c at base+step*c.
__device__ __forceinline__ void stage_store(float2* wl, const float2* v, float2 w1,
                                            int base, int step){
    constexpr int br[8] = {0,4,2,6,1,5,3,7};
    wl[LADDR(base)] = v[0];
    float2 p = w1;
    #pragma unroll
    for (int c = 1; c < 8; ++c) {
        wl[LADDR(base + step*c)] = cmul(v[br[c]], p);
        p = cmul(p, w1);
    }
}

__device__ __forceinline__ void stage_load(const float2* wl, float2* v, int j){
    #pragma unroll
    for (int i = 0; i < 8; ++i) v[i] = wl[LADDR(j + 64*i)];
}

// ---------------- sector map (matches reference _polar_masks) ----------------
__device__ __forceinline__ int sector_id(int hm, int wm) {
    const float step = 2.0f / 511.0f;
    float y = -1.0f + step * (float)hm;
    float x = -1.0f + step * (float)wm;
    float radius = sqrtf(x * x + y * y);
    float r = radius / sqrtf(2.0f);
    float a = atan2f(y, x);
    a = fmodf(a, PI_F);
    if (a < 0.0f) a += PI_F;

    const float rstep = (0.9f - 0.08f) / 3.0f;
    const float re0 = 0.08f;
    const float re1 = 0.08f + rstep;
    const float re2 = 0.08f + 2.0f * rstep;
    const float re3 = 0.9f;
    int rb;
    if      (r >= re0 && r < re1)  rb = 0;
    else if (r >= re1 && r < re2)  rb = 1;
    else if (r >= re2 && r <= re3) rb = 2;
    else return -1;

    const float astep = PI_F / 8.0f;
    int ab = 7;
    #pragma unroll
    for (int i = 0; i < 7; ++i) {
        float t0 = astep * (float)i;
        float t1 = astep * (float)(i + 1);
        if (a >= t0 && a < t1) { ab = i; break; }
    }
    return rb * 8 + ab;
}

__device__ __forceinline__ float hannf(int i) {
    return 0.5f * (1.0f - __cosf(TWO_PI_F * (float)i / 511.0f));
}

__device__ __forceinline__ float4 lum4(float4 r, float4 g, float4 b){
    return make_float4(0.2989f*r.x + 0.587f*g.x + 0.114f*b.x,
                       0.2989f*r.y + 0.587f*g.y + 0.114f*b.y,
                       0.2989f*r.z + 0.587f*g.z + 0.114f*b.z,
                       0.2989f*r.w + 0.587f*g.w + 0.114f*b.w);
}

// ---------------- kernel 1: luma + window + row FFT, radix-8 wave-sync ----------------
// Block = 4 waves; each wave FFTs one packed row-pair (h0 real, h1 imag).
// Inputs loaded as 12 float4/lane in ONE VMEM batch (launch_bounds lifts VGPR
// cap to 128), redistributed through wave-private LDS. Output staged through a
// TSWZ-swizzled block transpose -> 64B-contiguous global stores.
__global__ __launch_bounds__(256, 4) void rowfft_kernel(const float* __restrict__ pred,
                                                        const float* __restrict__ tgt,
                                                        float4* __restrict__ out4,
                                                        unsigned char* __restrict__ mapT,
                                                        float* __restrict__ counts) {
    __shared__ float2 lds[4 * 576];
    __shared__ float cbins[4 * 24];
    int blk = blockIdx.x;                 // 2048 = 32 img * 64
    int img = blk >> 6;
    int pb  = blk & 63;
    int t = threadIdx.x;
    int wv = t >> 6, j = t & 63;
    int hp = pb * 4 + wv;                 // row-pair index [0,256)
    int h0 = 2 * hp;
    float2* wl = lds + wv * 576;
    float* wc = cbins + wv * 24;

    if (j < 24) wc[j] = 0.0f;             // wave-local; DS in-order, no barrier
    if (j < 32) {                         // folded sector map + counts: 32 px/wave
        int idx = (blk * 4 + wv) * 32 + j;    // idx = wm*512 + hm
        int wm = idx >> 9, hm = idx & 511;
        int s = sector_id(hm, wm);
        mapT[idx] = (unsigned char)(s < 0 ? 255 : s);
        if (s >= 0) atomicAdd(&wc[s], 1.0f);
    }

    const float* base = (img < 16) ? (pred + (size_t)img * 786432)
                                   : (tgt  + (size_t)(img - 16) * 786432);
    // rows h0,h1 x 3 channels as float4: one batched VMEM round trip.
    const float4* c0 = (const float4*)(base + (size_t)h0 * 512);
    const float4* c1 = c0 + 65536;        // +262144 floats (G channel)
    const float4* c2 = c0 + 131072;       // +524288 floats (B channel)
    float4 ra0=c0[j], ra1=c0[j+64], ra2=c0[j+128], ra3=c0[j+192];
    float4 ga0=c1[j], ga1=c1[j+64], ga2=c1[j+128], ga3=c1[j+192];
    float4 ba0=c2[j], ba1=c2[j+64], ba2=c2[j+128], ba3=c2[j+192];
    float4 Llo0 = lum4(ra0, ga0, ba0);    // row h0, w = 4j..4j+3
    float4 Lhi0 = lum4(ra1, ga1, ba1);    // row h0, w = 256+4j..
    float4 Llo1 = lum4(ra2, ga2, ba2);    // row h1, w = 4j..4j+3
    float4 Lhi1 = lum4(ra3, ga3, ba3);    // row h1, w = 256+4j..
    float wh0 = hannf(h0), wh1 = hannf(h0 + 1);
    const float* pl0 = &Llo0.x; const float* ph0 = &Lhi0.x;
    const float* pl1 = &Llo1.x; const float* ph1 = &Lhi1.x;
    #pragma unroll
    for (int d = 0; d < 4; ++d) {
        int wlo = 4 * j + d;
        float hwlo = hannf(wlo);
        wl[LADDR(wlo)] = make_float2(pl0[d] * (wh0 * hwlo), pl1[d] * (wh1 * hwlo));
        int whi = 256 + wlo;
        float hwhi = hannf(whi);
        wl[LADDR(whi)] = make_float2(ph0[d] * (wh0 * hwhi), ph1[d] * (wh1 * hwhi));
    }
    CFENCE();
    float2 v[8];
    stage_load(wl, v, j);                 // redistribute: v[i] = x[j+64i]
    CFENCE();                             // reads precede stage-0 writes (in-order DS)
    float sn, cs;
    dft8(v);
    __sincosf(-TWO_PI_F * (float)j / 512.0f, &sn, &cs);
    stage_store(wl, v, make_float2(cs, sn), 8 * j, 1);
    CFENCE();
    stage_load(wl, v, j);
    CFENCE();
    dft8(v);
    __sincosf(-TWO_PI_F * (float)((j >> 3) << 3) / 512.0f, &sn, &cs);
    stage_store(wl, v, make_float2(cs, sn), (j & 7) + 64 * (j >> 3), 8);
    CFENCE();
    stage_load(wl, v, j);
    CFENCE();
    dft8(v);
    constexpr int br[8] = {0,4,2,6,1,5,3,7};
    int partner = (64 - j) & 63;
    float4 o[4];
    // Hermitian unpack: Z[512-k]: lane 64-j slot 7-c (j>0) / lane 0 slot (8-c)&7 (j==0)
    #pragma unroll
    for (int c = 0; c < 4; ++c) {
        float2 zk = v[br[c]];
        float mx = __shfl(v[br[7 - c]].x, partner, 64);
        float my = __shfl(v[br[7 - c]].y, partner, 64);
        float2 zs = v[br[(8 - c) & 7]];
        float2 zm = make_float2(j == 0 ? zs.x : mx, j == 0 ? zs.y : my);
        o[c] = make_float4(0.5f*(zk.x+zm.x), 0.5f*(zk.y-zm.y),
                           0.5f*(zk.y+zm.y), 0.5f*(zm.x-zk.x));
    }
    float4 oext;
    if (j == 0) {                         // k = 256 (self-conjugate)
        float2 z = v[br[4]];
        oext = make_float4(z.x, 0.0f, z.y, 0.0f);
    }
    CFENCE();                             // flush per-wave counts (wave-local)
    if (j < 24) {
        float c = wc[j];
        if (c != 0.0f) atomicAdd(&counts[j], c);
    }
    // block transpose (TSWZ-swizzled, conflict-free both phases)
    __syncthreads();
    float4* trans = (float4*)lds;         // 1028 float4 <= 2304 available
    #pragma unroll
    for (int c = 0; c < 4; ++c) trans[TSWZ((j + 64 * c) * 4 + wv)] = o[c];
    if (j == 0) trans[TSWZ(1024 + wv)] = oext;
    __syncthreads();
    size_t kb = (size_t)img * 257;
    int hpb = pb * 4;
    #pragma unroll
    for (int m = 0; m < 4; ++m) {
        int idx = t + 256 * m;            // 0..1023
        out4[(kb + (idx >> 2)) * 256 + hpb + (idx & 3)] = trans[TSWZ(idx)];
    }
    if (t < 4) out4[(kb + 256) * 256 + hpb + t] = trans[TSWZ(1024 + t)];
}

// ---------------- kernel 2: column FFT + log-mag + sector bins + fused epilogue ----
// One wave per (img, w) column, w in [0,256]; Hermitian mirror covers [257,511].
// 16 bank-spread bin replicas; barrier-free main body. The LAST block to finish
// (device-scope done counter) computes energies->charbonnier->mean in-place.
#define NREP 16
__global__ __launch_bounds__(256) void colfft_kernel(const float2* __restrict__ buf,
                                                     const unsigned char* __restrict__ mapT,
                                                     float* __restrict__ acc,
                                                     const float* __restrict__ counts,
                                                     const float* __restrict__ rw,
                                                     float* __restrict__ out,
                                                     int* __restrict__ done) {
    __shared__ float2 lds[4 * 576];
    __shared__ float bins[4 * NREP * 25];
    __shared__ int amLast;
    int t = threadIdx.x;
    int wv = t >> 6, j = t & 63;
    int gid = blockIdx.x * 4 + wv;        // 0 .. 8223
    int img = gid / 257;
    int w = gid - img * 257;
    float2* wl = lds + wv * 576;
    float* wb = bins + wv * NREP * 25;
    for (int i = j; i < NREP * 25; i += 64) wb[i] = 0.0f;
    const float2* col = buf + (size_t)gid * 512;
    float2 v[8];
    #pragma unroll
    for (int i = 0; i < 8; ++i) v[i] = col[j + 64 * i];
    float sn, cs;
    dft8(v);
    __sincosf(-TWO_PI_F * (float)j / 512.0f, &sn, &cs);
    stage_store(wl, v, make_float2(cs, sn), 8 * j, 1);
    CFENCE();
    stage_load(wl, v, j);
    CFENCE();
    dft8(v);
    __sincosf(-TWO_PI_F * (float)((j >> 3) << 3) / 512.0f, &sn, &cs);
    stage_store(wl, v, make_float2(cs, sn), (j & 7) + 64 * (j >> 3), 8);
    CFENCE();
    stage_load(wl, v, j);
    CFENCE();
    dft8(v);
    constexpr int br[8] = {0,4,2,6,1,5,3,7};
    const unsigned char* mw  = mapT + (size_t)((w + 256) & 511) * 512;
    const unsigned char* mw2 = mapT + (size_t)((256 - w) & 511) * 512;
    bool mir = (w >= 1 && w <= 255);
    int rep = (j & (NREP - 1)) * 25;      // 25*r mod 32 distinct for r in [0,16)
    #pragma unroll
    for (int c = 0; c < 8; ++c) {
        float2 z = v[br[c]];              // Z[h = j + 64c]
        float mag = log1pf(sqrtf(z.x * z.x + z.y * z.y));
        int hm = j + 64 * ((c + 4) & 7);  // (h+256)&511
        int s1 = mw[hm];
        if (s1 < 24) atomicAdd(&wb[rep + s1], mag);
        if (mir) {
            int hm2 = (256 - (j + 64 * c)) & 511;
            int s2 = mw2[hm2];
            if (s2 < 24) atomicAdd(&wb[rep + s2], mag);
        }
    }
    CFENCE();                             // wave-local: atomics precede these reads
    if (j < 24) {
        float sum = 0.0f;
        #pragma unroll
        for (int r = 0; r < NREP; ++r) sum += wb[r * 25 + j];
        atomicAdd(&acc[img * 24 + j], sum);
    }
    // ---- last-block-done fused epilogue ----
    __threadfence();
    if (t == 0) amLast = (atomicAdd(done, 1) == (int)gridDim.x - 1);
    __syncthreads();
    if (!amLast) return;
    float* fl = (float*)lds;              // FFT data dead; reuse 1152 floats
    float* ep = fl; float* et = fl + 384; float* red = fl + 768;
    for (int x = t; x < 384; x += 256) {  // x = b*24 + s
        int b = x / 24, s = x % 24;
        float cnt = fmaxf(counts[s], 1e-6f);
        // read other blocks' device-scope atomics via RMW (XCD-coherent)
        ep[x] = atomicAdd(&acc[b * 24 + s], 0.0f) / cnt;
        et[x] = atomicAdd(&acc[(16 + b) * 24 + s], 0.0f) / cnt;
    }
    __syncthreads();
    for (int x = t; x < 384; x += 256) {
        int b = x / 24, s = x % 24, r = s >> 3;
        int gbase = b * 24 + r * 8;
        float sp = 0.0f, st2 = 0.0f;
        #pragma unroll
        for (int a = 0; a < 8; ++a) { sp += ep[gbase + a]; st2 += et[gbase + a]; }
        float pe = ep[x] / fmaxf(sp, 1e-6f);
        float te = et[x] / fmaxf(st2, 1e-6f);
        float d = pe - te;
        red[x] = sqrtf(d * d + 1e-6f) * rw[r];
    }
    __syncthreads();
    if (t < 128) red[t] += red[t + 128] + red[t + 256];
    __syncthreads();
    if (t < 64) {
        float vsum = red[t] + red[t + 64];
        #pragma unroll
        for (int o = 32; o > 0; o >>= 1) vsum += __shfl_down(vsum, o, 64);
        if (t == 0) out[0] = vsum / 384.0f;
    }
}

extern "C" void kernel_launch(void* const* d_in, const int* in_sizes, int n_in,
                              void* d_out, int out_size, void* d_ws, size_t ws_size,
                              hipStream_t stream) {
    const float* pred = (const float*)d_in[0];
    const float* tgt  = (const float*)d_in[1];
    const float* rw   = (const float*)d_in[2];

    char* ws = (char*)d_ws;
    float* acc    = (float*)ws;                     // 768 floats @ 0
    float* counts = (float*)(ws + 3072);            // 24 floats
    int*   done   = (int*)(ws + 3200);              // completion counter
    unsigned char* mapT = (unsigned char*)(ws + 4096);      // 512*512 = 256 KB
    float2* buf   = (float2*)(ws + 4096 + 262144);  // 32*257*512 complex = 33.7 MB

    hipMemsetAsync(ws, 0, 4096, stream);            // acc + counts + done
    rowfft_kernel<<<32 * 64, 256, 0, stream>>>(pred, tgt, (float4*)buf, mapT, counts);
    colfft_kernel<<<2056, 256, 0, stream>>>(buf, mapT, acc, counts, rw,
                                            (float*)d_out, done);
}

// Round 7
// 241.022 us; speedup vs baseline: 1.4036x; 1.4036x over previous
//
#include <hip/hip_runtime.h>
#include <math.h>

#define PI_F 3.14159265358979323846f
#define TWO_PI_F 6.28318530717958647692f
#define RSQ2 0.70710678118654752440f

// Compiler-only fence: stops IR/scheduler reordering of LDS ops across it.
// HW ordering is free: a wave's DS ops execute in order, and the backend
// inserts minimal s_waitcnt lgkmcnt(N) before VALU use of loaded values.
#define CFENCE() __asm__ volatile("" ::: "memory")
// additive swizzle for FFT stage arrays: injective on [0,512), max 574.
#define LADDR(a) ((a) + ((a) >> 3))
// XOR swizzle for the output transpose (float4 units): bijective, spreads
// lane-stride-16 writes across all 8 float4-bank-groups -> 2 lanes/bank (free).
#define TSWZ(L) ((L) ^ (((L) >> 4) & 7))

__device__ __forceinline__ float2 cadd(float2 a, float2 b){ return make_float2(a.x+b.x, a.y+b.y); }
__device__ __forceinline__ float2 csub(float2 a, float2 b){ return make_float2(a.x-b.x, a.y-b.y); }
__device__ __forceinline__ float2 cmul(float2 a, float2 b){ return make_float2(a.x*b.x - a.y*b.y, a.x*b.y + a.y*b.x); }
__device__ __forceinline__ float2 cw1(float2 a){ return make_float2(RSQ2*(a.x+a.y), RSQ2*(a.y-a.x)); }  // *W8^1
__device__ __forceinline__ float2 cw2(float2 a){ return make_float2(a.y, -a.x); }                        // *(-i)
__device__ __forceinline__ float2 cw3(float2 a){ return make_float2(RSQ2*(a.y-a.x), -RSQ2*(a.x+a.y)); }  // *W8^3

// in-place DIF-8. On return, slot m holds U_{br[m]}, br = {0,4,2,6,1,5,3,7}.
__device__ __forceinline__ void dft8(float2* v){
    float2 a0=cadd(v[0],v[4]), a1=cadd(v[1],v[5]), a2=cadd(v[2],v[6]), a3=cadd(v[3],v[7]);
    float2 b0=csub(v[0],v[4]);
    float2 b1=cw1(csub(v[1],v[5]));
    float2 b2=cw2(csub(v[2],v[6]));
    float2 b3=cw3(csub(v[3],v[7]));
    float2 c0=cadd(a0,a2), c2=csub(a0,a2), c1=cadd(a1,a3), c3=cw2(csub(a1,a3));
    float2 d0=cadd(b0,b2), d2=csub(b0,b2), d1=cadd(b1,b3), d3=cw2(csub(b1,b3));
    v[0]=cadd(c0,c1); v[1]=csub(c0,c1);   // U0, U4
    v[2]=cadd(c2,c3); v[3]=csub(c2,c3);   // U2, U6
    v[4]=cadd(d0,d1); v[5]=csub(d0,d1);   // U1, U5
    v[6]=cadd(d2,d3); v[7]=csub(d2,d3);   // U3, U7
}

// Stockham radix-8 stage store: address-slot c gets U_c * w1^c at base+step*c.
__device__ __forceinline__ void stage_store(float2* wl, const float2* v, float2 w1,
                                            int base, int step){
    constexpr int br[8] = {0,4,2,6,1,5,3,7};
    wl[LADDR(base)] = v[0];
    float2 p = w1;
    #pragma unroll
    for (int c = 1; c < 8; ++c) {
        wl[LADDR(base + step*c)] = cmul(v[br[c]], p);
        p = cmul(p, w1);
    }
}

__device__ __forceinline__ void stage_load(const float2* wl, float2* v, int j){
    #pragma unroll
    for (int i = 0; i < 8; ++i) v[i] = wl[LADDR(j + 64*i)];
}

// ---------------- sector map (matches reference _polar_masks) ----------------
__device__ __forceinline__ int sector_id(int hm, int wm) {
    const float step = 2.0f / 511.0f;
    float y = -1.0f + step * (float)hm;
    float x = -1.0f + step * (float)wm;
    float radius = sqrtf(x * x + y * y);
    float r = radius / sqrtf(2.0f);
    float a = atan2f(y, x);
    a = fmodf(a, PI_F);
    if (a < 0.0f) a += PI_F;

    const float rstep = (0.9f - 0.08f) / 3.0f;
    const float re0 = 0.08f;
    const float re1 = 0.08f + rstep;
    const float re2 = 0.08f + 2.0f * rstep;
    const float re3 = 0.9f;
    int rb;
    if      (r >= re0 && r < re1)  rb = 0;
    else if (r >= re1 && r < re2)  rb = 1;
    else if (r >= re2 && r <= re3) rb = 2;
    else return -1;

    const float astep = PI_F / 8.0f;
    int ab = 7;
    #pragma unroll
    for (int i = 0; i < 7; ++i) {
        float t0 = astep * (float)i;
        float t1 = astep * (float)(i + 1);
        if (a >= t0 && a < t1) { ab = i; break; }
    }
    return rb * 8 + ab;
}

__device__ __forceinline__ float hannf(int i) {
    return 0.5f * (1.0f - __cosf(TWO_PI_F * (float)i / 511.0f));
}

__device__ __forceinline__ float4 lum4(float4 r, float4 g, float4 b){
    return make_float4(0.2989f*r.x + 0.587f*g.x + 0.114f*b.x,
                       0.2989f*r.y + 0.587f*g.y + 0.114f*b.y,
                       0.2989f*r.z + 0.587f*g.z + 0.114f*b.z,
                       0.2989f*r.w + 0.587f*g.w + 0.114f*b.w);
}

// ---------------- kernel 1: luma + window + row FFT, radix-8 wave-sync ----------------
// Block = 4 waves; each wave FFTs one packed row-pair (h0 real, h1 imag).
// Inputs loaded as 12 float4/lane in one VMEM batch; components consumed
// EXPLICITLY (no pointer-indexing of register float4s -> no scratch demotion).
// Output staged through a TSWZ-swizzled block transpose -> 64B global stores.
__global__ __launch_bounds__(256) void rowfft_kernel(const float* __restrict__ pred,
                                                     const float* __restrict__ tgt,
                                                     float4* __restrict__ out4,
                                                     unsigned char* __restrict__ mapT,
                                                     float* __restrict__ counts) {
    __shared__ float2 lds[4 * 576];
    __shared__ float cbins[4 * 24];
    int blk = blockIdx.x;                 // 2048 = 32 img * 64
    int img = blk >> 6;
    int pb  = blk & 63;
    int t = threadIdx.x;
    int wv = t >> 6, j = t & 63;
    int hp = pb * 4 + wv;                 // row-pair index [0,256)
    int h0 = 2 * hp;
    float2* wl = lds + wv * 576;
    float* wc = cbins + wv * 24;

    if (j < 24) wc[j] = 0.0f;             // wave-local; DS in-order, no barrier
    if (j < 32) {                         // folded sector map + counts: 32 px/wave
        int idx = (blk * 4 + wv) * 32 + j;    // idx = wm*512 + hm
        int wm = idx >> 9, hm = idx & 511;
        int s = sector_id(hm, wm);
        mapT[idx] = (unsigned char)(s < 0 ? 255 : s);
        if (s >= 0) atomicAdd(&wc[s], 1.0f);
    }

    const float* base = (img < 16) ? (pred + (size_t)img * 786432)
                                   : (tgt  + (size_t)(img - 16) * 786432);
    // rows h0,h1 x 3 channels as float4: one batched VMEM round trip.
    const float4* c0 = (const float4*)(base + (size_t)h0 * 512);
    const float4* c1 = c0 + 65536;        // +262144 floats (G channel)
    const float4* c2 = c0 + 131072;       // +524288 floats (B channel)
    float4 ra0=c0[j], ra1=c0[j+64], ra2=c0[j+128], ra3=c0[j+192];
    float4 ga0=c1[j], ga1=c1[j+64], ga2=c1[j+128], ga3=c1[j+192];
    float4 ba0=c2[j], ba1=c2[j+64], ba2=c2[j+128], ba3=c2[j+192];
    float4 Llo0 = lum4(ra0, ga0, ba0);    // row h0, w = 4j..4j+3
    float4 Lhi0 = lum4(ra1, ga1, ba1);    // row h0, w = 256+4j..
    float4 Llo1 = lum4(ra2, ga2, ba2);    // row h1, w = 4j..4j+3
    float4 Lhi1 = lum4(ra3, ga3, ba3);    // row h1, w = 256+4j..
    float wh0 = hannf(h0), wh1 = hannf(h0 + 1);
    {
        int w0 = 4 * j;
        float e0 = hannf(w0),     e1 = hannf(w0 + 1);
        float e2 = hannf(w0 + 2), e3 = hannf(w0 + 3);
        wl[LADDR(w0 + 0)] = make_float2(Llo0.x * (wh0 * e0), Llo1.x * (wh1 * e0));
        wl[LADDR(w0 + 1)] = make_float2(Llo0.y * (wh0 * e1), Llo1.y * (wh1 * e1));
        wl[LADDR(w0 + 2)] = make_float2(Llo0.z * (wh0 * e2), Llo1.z * (wh1 * e2));
        wl[LADDR(w0 + 3)] = make_float2(Llo0.w * (wh0 * e3), Llo1.w * (wh1 * e3));
        int w1 = w0 + 256;
        float f0 = hannf(w1),     f1 = hannf(w1 + 1);
        float f2 = hannf(w1 + 2), f3 = hannf(w1 + 3);
        wl[LADDR(w1 + 0)] = make_float2(Lhi0.x * (wh0 * f0), Lhi1.x * (wh1 * f0));
        wl[LADDR(w1 + 1)] = make_float2(Lhi0.y * (wh0 * f1), Lhi1.y * (wh1 * f1));
        wl[LADDR(w1 + 2)] = make_float2(Lhi0.z * (wh0 * f2), Lhi1.z * (wh1 * f2));
        wl[LADDR(w1 + 3)] = make_float2(Lhi0.w * (wh0 * f3), Lhi1.w * (wh1 * f3));
    }
    CFENCE();
    float2 v[8];
    stage_load(wl, v, j);                 // redistribute: v[i] = x[j+64i]
    CFENCE();                             // reads precede stage-0 writes (in-order DS)
    float sn, cs;
    dft8(v);
    __sincosf(-TWO_PI_F * (float)j / 512.0f, &sn, &cs);
    stage_store(wl, v, make_float2(cs, sn), 8 * j, 1);
    CFENCE();
    stage_load(wl, v, j);
    CFENCE();
    dft8(v);
    __sincosf(-TWO_PI_F * (float)((j >> 3) << 3) / 512.0f, &sn, &cs);
    stage_store(wl, v, make_float2(cs, sn), (j & 7) + 64 * (j >> 3), 8);
    CFENCE();
    stage_load(wl, v, j);
    CFENCE();
    dft8(v);
    constexpr int br[8] = {0,4,2,6,1,5,3,7};
    int partner = (64 - j) & 63;
    float4 o0, o1, o2, o3;
    // Hermitian unpack: Z[512-k]: lane 64-j slot 7-c (j>0) / lane 0 slot (8-c)&7 (j==0)
    {
        float2 zk = v[br[0]];
        float mx = __shfl(v[br[7]].x, partner, 64);
        float my = __shfl(v[br[7]].y, partner, 64);
        float2 zm = make_float2(j == 0 ? v[br[0]].x : mx, j == 0 ? v[br[0]].y : my);
        o0 = make_float4(0.5f*(zk.x+zm.x), 0.5f*(zk.y-zm.y),
                         0.5f*(zk.y+zm.y), 0.5f*(zm.x-zk.x));
    }
    {
        float2 zk = v[br[1]];
        float mx = __shfl(v[br[6]].x, partner, 64);
        float my = __shfl(v[br[6]].y, partner, 64);
        float2 zm = make_float2(j == 0 ? v[br[7]].x : mx, j == 0 ? v[br[7]].y : my);
        o1 = make_float4(0.5f*(zk.x+zm.x), 0.5f*(zk.y-zm.y),
                         0.5f*(zk.y+zm.y), 0.5f*(zm.x-zk.x));
    }
    {
        float2 zk = v[br[2]];
        float mx = __shfl(v[br[5]].x, partner, 64);
        float my = __shfl(v[br[5]].y, partner, 64);
        float2 zm = make_float2(j == 0 ? v[br[6]].x : mx, j == 0 ? v[br[6]].y : my);
        o2 = make_float4(0.5f*(zk.x+zm.x), 0.5f*(zk.y-zm.y),
                         0.5f*(zk.y+zm.y), 0.5f*(zm.x-zk.x));
    }
    {
        float2 zk = v[br[3]];
        float mx = __shfl(v[br[4]].x, partner, 64);
        float my = __shfl(v[br[4]].y, partner, 64);
        float2 zm = make_float2(j == 0 ? v[br[5]].x : mx, j == 0 ? v[br[5]].y : my);
        o3 = make_float4(0.5f*(zk.x+zm.x), 0.5f*(zk.y-zm.y),
                         0.5f*(zk.y+zm.y), 0.5f*(zm.x-zk.x));
    }
    float4 oext;
    if (j == 0) {                         // k = 256 (self-conjugate)
        float2 z = v[br[4]];
        oext = make_float4(z.x, 0.0f, z.y, 0.0f);
    }
    CFENCE();                             // flush per-wave counts (wave-local)
    if (j < 24) {
        float c = wc[j];
        if (c != 0.0f) atomicAdd(&counts[j], c);
    }
    // block transpose (TSWZ-swizzled, conflict-free both phases)
    __syncthreads();
    float4* trans = (float4*)lds;         // 1028 float4 <= 2304 available
    trans[TSWZ((j      ) * 4 + wv)] = o0;
    trans[TSWZ((j +  64) * 4 + wv)] = o1;
    trans[TSWZ((j + 128) * 4 + wv)] = o2;
    trans[TSWZ((j + 192) * 4 + wv)] = o3;
    if (j == 0) trans[TSWZ(1024 + wv)] = oext;
    __syncthreads();
    size_t kb = (size_t)img * 257;
    int hpb = pb * 4;
    #pragma unroll
    for (int m = 0; m < 4; ++m) {
        int idx = t + 256 * m;            // 0..1023
        out4[(kb + (idx >> 2)) * 256 + hpb + (idx & 3)] = trans[TSWZ(idx)];
    }
    if (t < 4) out4[(kb + 256) * 256 + hpb + t] = trans[TSWZ(1024 + t)];
}

// ---------------- kernel 2: column FFT + log-mag + sector bins ----------------
// One wave per (img, w) column, w in [0,256]; Hermitian mirror covers [257,511].
// 8 bank-spread bin replicas (proven R4 config); barrier-free; no epilogue
// (the last-block fused epilogue's __threadfence cost ~100us in R6 — reverted).
#define NREP 8
__global__ __launch_bounds__(256) void colfft_kernel(const float2* __restrict__ buf,
                                                     const unsigned char* __restrict__ mapT,
                                                     float* __restrict__ acc) {
    __shared__ float2 lds[4 * 576];
    __shared__ float bins[4 * NREP * 25];
    int t = threadIdx.x;
    int wv = t >> 6, j = t & 63;
    int gid = blockIdx.x * 4 + wv;        // 0 .. 8223
    int img = gid / 257;
    int w = gid - img * 257;
    float2* wl = lds + wv * 576;
    float* wb = bins + wv * NREP * 25;
    for (int i = j; i < NREP * 25; i += 64) wb[i] = 0.0f;
    const float2* col = buf + (size_t)gid * 512;
    float2 v[8];
    #pragma unroll
    for (int i = 0; i < 8; ++i) v[i] = col[j + 64 * i];
    float sn, cs;
    dft8(v);
    __sincosf(-TWO_PI_F * (float)j / 512.0f, &sn, &cs);
    stage_store(wl, v, make_float2(cs, sn), 8 * j, 1);
    CFENCE();
    stage_load(wl, v, j);
    CFENCE();
    dft8(v);
    __sincosf(-TWO_PI_F * (float)((j >> 3) << 3) / 512.0f, &sn, &cs);
    stage_store(wl, v, make_float2(cs, sn), (j & 7) + 64 * (j >> 3), 8);
    CFENCE();
    stage_load(wl, v, j);
    CFENCE();
    dft8(v);
    constexpr int br[8] = {0,4,2,6,1,5,3,7};
    const unsigned char* mw  = mapT + (size_t)((w + 256) & 511) * 512;
    const unsigned char* mw2 = mapT + (size_t)((256 - w) & 511) * 512;
    bool mir = (w >= 1 && w <= 255);
    int rep = (j & (NREP - 1)) * 25;      // 25*r mod 32 distinct for r in [0,8)
    #pragma unroll
    for (int c = 0; c < 8; ++c) {
        float2 z = v[br[c]];              // Z[h = j + 64c]
        float mag = log1pf(sqrtf(z.x * z.x + z.y * z.y));
        int hm = j + 64 * ((c + 4) & 7);  // (h+256)&511
        int s1 = mw[hm];
        if (s1 < 24) atomicAdd(&wb[rep + s1], mag);
        if (mir) {
            int hm2 = (256 - (j + 64 * c)) & 511;
            int s2 = mw2[hm2];
            if (s2 < 24) atomicAdd(&wb[rep + s2], mag);
        }
    }
    CFENCE();                             // wave-local: atomics precede these reads
    if (j < 24) {
        float sum = 0.0f;
        #pragma unroll
        for (int r = 0; r < NREP; ++r) sum += wb[r * 25 + j];
        atomicAdd(&acc[img * 24 + j], sum);
    }
}

// ---------------- kernel 3: energies -> charbonnier -> weighted mean ----------------
__global__ __launch_bounds__(384) void final_kernel(const float* __restrict__ acc,
                                                    const float* __restrict__ counts,
                                                    const float* __restrict__ rw,
                                                    float* __restrict__ out) {
    __shared__ float ep[384], et[384], red[384];
    int t = threadIdx.x;                  // t = b*24 + r*8 + a
    int b = t / 24;
    int s = t % 24;
    int r = s >> 3;
    float cnt = fmaxf(counts[s], 1e-6f);
    ep[t] = acc[b * 24 + s] / cnt;
    et[t] = acc[(16 + b) * 24 + s] / cnt;
    __syncthreads();
    int gbase = b * 24 + r * 8;
    float sp = 0.0f, st = 0.0f;
    #pragma unroll
    for (int a = 0; a < 8; ++a) { sp += ep[gbase + a]; st += et[gbase + a]; }
    float pe = ep[t] / fmaxf(sp, 1e-6f);
    float te = et[t] / fmaxf(st, 1e-6f);
    float d = pe - te;
    float dist = sqrtf(d * d + 1e-6f);
    red[t] = dist * rw[r];
    __syncthreads();
    if (t < 128) red[t] += red[t + 128] + red[t + 256];
    __syncthreads();
    if (t < 64) {
        float v = red[t] + red[t + 64];
        #pragma unroll
        for (int o = 32; o > 0; o >>= 1) v += __shfl_down(v, o, 64);
        if (t == 0) out[0] = v / 384.0f;
    }
}

extern "C" void kernel_launch(void* const* d_in, const int* in_sizes, int n_in,
                              void* d_out, int out_size, void* d_ws, size_t ws_size,
                              hipStream_t stream) {
    const float* pred = (const float*)d_in[0];
    const float* tgt  = (const float*)d_in[1];
    const float* rw   = (const float*)d_in[2];

    char* ws = (char*)d_ws;
    float* acc    = (float*)ws;                     // 768 floats @ 0
    float* counts = (float*)(ws + 3072);            // 24 floats
    unsigned char* mapT = (unsigned char*)(ws + 4096);      // 512*512 = 256 KB
    float2* buf   = (float2*)(ws + 4096 + 262144);  // 32*257*512 complex = 33.7 MB

    hipMemsetAsync(ws, 0, 4096, stream);            // acc + counts
    rowfft_kernel<<<32 * 64, 256, 0, stream>>>(pred, tgt, (float4*)buf, mapT, counts);
    colfft_kernel<<<2056, 256, 0, stream>>>(buf, mapT, acc);
    final_kernel<<<1, 384, 0, stream>>>(acc, counts, rw, (float*)d_out);
}